// Round 5
// baseline (45.535 us; speedup 1.0000x reference)
//
#include <hip/hip_runtime.h>
#include <hip/hip_bf16.h>

typedef __bf16 bf16;
typedef bf16  bf16x2 __attribute__((ext_vector_type(2)));
typedef bf16  bf16x4 __attribute__((ext_vector_type(4)));
typedef bf16  bf16x8 __attribute__((ext_vector_type(8)));
typedef float f32x4  __attribute__((ext_vector_type(4)));
typedef float f32x16 __attribute__((ext_vector_type(16)));

#define MFMA32(A, B, C) __builtin_amdgcn_mfma_f32_32x32x16_bf16((A), (B), (C), 0, 0, 0)

namespace {
constexpr int   kS = 2048, kHq = 16, kHkv = 8, kD = 128, kChunk = 512;
constexpr int   kStrK  = kHkv * kD;                        // floats between keys
constexpr float kLog2e = 1.4426950408889634f;
constexpr float kScale = 0.08838834764831845f * kLog2e;    // exp2-domain softmax
constexpr float kThr   = 8.0f * kLog2e;                    // T13 threshold (log2)
}

union U32B { bf16x2 h; unsigned u; };
union PAU  { unsigned u[4]; bf16x8 v; };

// lgkm-only barrier: LDS ops drained, VMEM prefetch stays in flight (T4-lite).
__device__ __forceinline__ void lgkm_barrier() {
  __builtin_amdgcn_sched_barrier(0);
  asm volatile("s_waitcnt lgkmcnt(0)" ::: "memory");
  __builtin_amdgcn_s_barrier();
  __builtin_amdgcn_sched_barrier(0);
}

// Swapped-QK^T chunked-causal GQA attention.
// 512 blocks (b,n,hq,j) x 256 threads (4 waves x 32 q-rows) => 2 blocks/CU.
// S^T = K*Q^T -> lane owns q = lane&31; softmax lane-local (exp2 domain).
// O^T = V^T*P^T -> q stays lane-local for rescale/divide.
__global__ __launch_bounds__(256, 2)
void attn_chunk(const float* __restrict__ Qg, const float* __restrict__ Kg,
                const float* __restrict__ Vg, float* __restrict__ Og) {
  __shared__ __attribute__((aligned(16))) bf16 ldsK[2][64 * 128];  // [key][d] ^((key&7)<<3)
  __shared__ __attribute__((aligned(16))) bf16 ldsV[2][128 * 64];  // [d][key] ^((d&7)<<3)

  const int t = threadIdx.x, lane = t & 63, w = t >> 6;
  const int l31 = lane & 31, hi = lane >> 5;

  // XCD grouping: 64 blocks of one (b,n) per XCD (K/V ~4MB => L2-local).
  const int bid = blockIdx.x;
  const int gid = (bid & 7) * 64 + (bid >> 3);
  const int j = gid & 3, hq = (gid >> 2) & 15, n = (gid >> 6) & 3, b = (gid >> 8) & 1;
  const int h = hq >> 1;

  // Pair-balanced strips: {j, 15-j, 7-j, 8+j} -> 18 wave-tiles per block.
  const int strip   = (w == 0) ? j : (w == 1) ? (15 - j) : (w == 2) ? (7 - j) : (8 + j);
  const int need    = (strip >> 1) + 1;       // kv tiles this wave computes
  const int maxNeed = 8 - (j >> 1);           // kv tiles staged by this block
  const int qg      = n * kChunk + strip * 32 + l31;   // global q row (lane-local)
  const int rowoff  = 32 * (strip & 1) + l31; // q offset within diagonal tile

  // ---- Q fragments: B-operand, col=q=l31, k = dk*16 + 8*hi + j ----
  bf16x8 qf[8];
  {
    const float* qp = Qg + ((size_t)(b * kS + qg) * kHq + hq) * kD;
#pragma unroll
    for (int dk = 0; dk < 8; ++dk) {
      f32x4 x0 = *(const f32x4*)(qp + dk * 16 + 8 * hi);
      f32x4 x1 = *(const f32x4*)(qp + dk * 16 + 8 * hi + 4);
      bf16x8 v;
#pragma unroll
      for (int q = 0; q < 4; ++q) { v[q] = (bf16)(x0[q] * kScale); v[4 + q] = (bf16)(x1[q] * kScale); }
      qf[dk] = v;
    }
  }

  f32x16 o[4];  // O^T accum: d = 32*dt + (r&3)+8*(r>>2)+4*hi, col q = l31
#pragma unroll
  for (int dt = 0; dt < 4; ++dt)
#pragma unroll
    for (int r = 0; r < 16; ++r) o[dt][r] = 0.f;
  float m = -1e30f, l = 0.f;

  const float* kpz = Kg + ((size_t)(b * kS + n * kChunk) * kHkv + h) * kD;
  const float* vpz = Vg + ((size_t)(b * kS + n * kChunk) * kHkv + h) * kD;

  // staging coords (256 threads / 64-key tile):
  const int sKey = t >> 5, sD4 = t & 31;   // K: key = 8*it + sKey, it 0..7
  const int vKp = t & 31, vD4h = t >> 5;   // V: keys {2vKp,2vKp+1}, d4 = 8*it + vD4h, it 0..3

  f32x4 kf[8], va[4], vb[4];  // T14 prefetch registers (64 VGPR)
  auto issue = [&](int kt) {
    const float* kp = kpz + (size_t)kt * 64 * kStrK;
    const float* vp = vpz + (size_t)kt * 64 * kStrK;
#pragma unroll
    for (int it = 0; it < 8; ++it)
      kf[it] = *(const f32x4*)(kp + (size_t)(8 * it + sKey) * kStrK + sD4 * 4);
#pragma unroll
    for (int it = 0; it < 4; ++it) {
      va[it] = *(const f32x4*)(vp + (size_t)(2 * vKp) * kStrK + (8 * it + vD4h) * 4);
      vb[it] = *(const f32x4*)(vp + (size_t)(2 * vKp + 1) * kStrK + (8 * it + vD4h) * 4);
    }
  };
  auto stage = [&](int buf) {
#pragma unroll
    for (int it = 0; it < 8; ++it) {
      const int key = 8 * it + sKey;
      bf16x4 kb;
#pragma unroll
      for (int q = 0; q < 4; ++q) kb[q] = (bf16)kf[it][q];
      *(bf16x4*)&ldsK[buf][key * 128 + ((sD4 * 4) ^ ((key & 7) << 3))] = kb;
    }
#pragma unroll
    for (int it = 0; it < 4; ++it) {
#pragma unroll
      for (int q = 0; q < 4; ++q) {
        const int d = (8 * it + vD4h) * 4 + q;
        U32B uu; uu.h = bf16x2{(bf16)va[it][q], (bf16)vb[it][q]};
        *(unsigned*)&ldsV[buf][d * 64 + ((2 * vKp) ^ ((d & 7) << 3))] = uu.u;
      }
    }
  };

  auto compute = [&](int buf, bool diag) {
    // ---- QK^T: S^T[key][q], 16 MFMA ----
    f32x16 s[2];
#pragma unroll
    for (int ks = 0; ks < 2; ++ks)
#pragma unroll
      for (int r = 0; r < 16; ++r) s[ks][r] = 0.f;
    __builtin_amdgcn_s_setprio(1);
#pragma unroll
    for (int ks = 0; ks < 2; ++ks) {
      const int key = ks * 32 + l31, swz = (key & 7) << 3;
      const bf16* kb = &ldsK[buf][key * 128];
#pragma unroll
      for (int dk = 0; dk < 8; ++dk) {
        bf16x8 kfr = *(const bf16x8*)&kb[(dk * 16 + 8 * hi) ^ swz];
        s[ks] = MFMA32(kfr, qf[dk], s[ks]);
      }
    }
    __builtin_amdgcn_s_setprio(0);
    if (diag) {
#pragma unroll
      for (int ks = 0; ks < 2; ++ks)
#pragma unroll
        for (int r = 0; r < 16; ++r) {
          const int key = ks * 32 + (r & 3) + 8 * (r >> 2) + 4 * hi;
          if (key > rowoff) s[ks][r] = -1e30f;
        }
    }
    // ---- lane-local softmax in exp2 domain (q = l31; partner = lane^32) ----
    float mx = -1e30f;
#pragma unroll
    for (int ks = 0; ks < 2; ++ks)
#pragma unroll
      for (int r = 0; r < 16; ++r) mx = fmaxf(mx, s[ks][r]);
    mx = fmaxf(mx, __shfl_xor(mx, 32, 64));
    if (__any(mx > m + kThr)) {  // T13 defer-max
      const float mn = fmaxf(m, mx), c = exp2f(m - mn);
      l *= c;
#pragma unroll
      for (int dt = 0; dt < 4; ++dt)
#pragma unroll
        for (int r = 0; r < 16; ++r) o[dt][r] *= c;
      m = mn;
    }
    unsigned u[2][8];
    float lp = 0.f;
#pragma unroll
    for (int ks = 0; ks < 2; ++ks)
#pragma unroll
      for (int q = 0; q < 8; ++q) {
        const float p0 = exp2f(s[ks][2 * q] - m), p1 = exp2f(s[ks][2 * q + 1] - m);
        lp += p0 + p1;
        U32B uu; uu.h = bf16x2{(bf16)p0, (bf16)p1};
        u[ks][q] = uu.u;
      }
    l += lp;
    // ---- half-exchange: interleaved-4 ownership -> contiguous-8 B-frags ----
    unsigned rc[2][4];
#pragma unroll
    for (int ks = 0; ks < 2; ++ks)
#pragma unroll
      for (int i = 0; i < 4; ++i)
        rc[ks][i] = (unsigned)__shfl_xor((int)u[ks][(i & 1) + 4 * (i >> 1) + (hi ? 0 : 2)], 32, 64);
    bf16x8 pa[4];
#pragma unroll
    for (int ks = 0; ks < 2; ++ks)
#pragma unroll
      for (int kh = 0; kh < 2; ++kh) {
        PAU pu;
        pu.u[0] = hi ? rc[ks][2 * kh]     : u[ks][4 * kh];
        pu.u[1] = hi ? rc[ks][2 * kh + 1] : u[ks][4 * kh + 1];
        pu.u[2] = hi ? u[ks][4 * kh + 2]  : rc[ks][2 * kh];
        pu.u[3] = hi ? u[ks][4 * kh + 3]  : rc[ks][2 * kh + 1];
        pa[ks * 2 + kh] = pu.v;
      }
    // ---- PV: O^T += V^T * P^T, 16 MFMA ----
    __builtin_amdgcn_s_setprio(1);
#pragma unroll
    for (int dt = 0; dt < 4; ++dt) {
      const int d = dt * 32 + l31, swz = (d & 7) << 3;
      const bf16* vbp = &ldsV[buf][d * 64];
#pragma unroll
      for (int ksl = 0; ksl < 4; ++ksl) {
        bf16x8 vfr = *(const bf16x8*)&vbp[(ksl * 16 + 8 * hi) ^ swz];
        o[dt] = MFMA32(vfr, pa[ksl], o[dt]);
      }
    }
    __builtin_amdgcn_s_setprio(0);
  };

  // ---- main loop: 1 lgkm-barrier/tile, dbuf LDS, VMEM in flight across it ----
  issue(0);
  stage(0);
  issue(1);
  lgkm_barrier();
#pragma unroll 1
  for (int kt = 0; kt < maxNeed; ++kt) {
    if (kt + 1 < maxNeed) {
      stage((kt + 1) & 1);
      if (kt + 2 < maxNeed) issue(kt + 2);
    }
    if (kt < need) compute(kt & 1, kt + 1 == need);
    if (kt + 1 < maxNeed) lgkm_barrier();
  }

  // ---- epilogue: combine partner l, divide, store O^T regs ----
  l += __shfl_xor(l, 32, 64);
  const float inv = 1.f / l;
  float* op = Og + ((size_t)(b * kS + qg) * kHq + hq) * kD;
#pragma unroll
  for (int dt = 0; dt < 4; ++dt)
#pragma unroll
    for (int rq = 0; rq < 4; ++rq) {
      f32x4 st;
#pragma unroll
      for (int rr = 0; rr < 4; ++rr) st[rr] = o[dt][4 * rq + rr] * inv;
      *(f32x4*)(op + dt * 32 + 8 * rq + 4 * hi) = st;
    }
}

extern "C" void kernel_launch(void* const* d_in, const int* in_sizes, int n_in,
                              void* d_out, int out_size, void* d_ws, size_t ws_size,
                              hipStream_t stream) {
  (void)in_sizes; (void)n_in; (void)d_ws; (void)ws_size; (void)out_size;
  const float* Q = (const float*)d_in[0];
  const float* K = (const float*)d_in[1];
  const float* V = (const float*)d_in[2];
  float* O = (float*)d_out;
  dim3 grid(512);   // (b2, n4, hq16, j4), XCD-grouped -> 2 blocks/CU
  dim3 block(256);  // 4 waves x 32 q-rows
  hipLaunchKernelGGL(attn_chunk, grid, block, 0, stream, Q, K, V, O);
}

// Round 6
// 34.892 us; speedup vs baseline: 1.3050x; 1.3050x over previous
//
#include <hip/hip_runtime.h>
#include <hip/hip_bf16.h>

typedef __bf16 bf16;
typedef bf16  bf16x2 __attribute__((ext_vector_type(2)));
typedef bf16  bf16x4 __attribute__((ext_vector_type(4)));
typedef bf16  bf16x8 __attribute__((ext_vector_type(8)));
typedef float f32x4  __attribute__((ext_vector_type(4)));

#define MFMA16(A, B, C) __builtin_amdgcn_mfma_f32_16x16x32_bf16((A), (B), (C), 0, 0, 0)

namespace {
constexpr int   kS = 2048, kHq = 16, kHkv = 8, kD = 128, kChunk = 512;
constexpr int   kStrK  = kHkv * kD;                       // floats between keys
constexpr float kLog2e = 1.4426950408889634f;
constexpr float kScale = 0.08838834764831845f * kLog2e;   // exp2-domain softmax
constexpr float kThr   = 8.0f * kLog2e;                   // T13 threshold (log2)
}

union U32B { bf16x2 h; unsigned u; };

// lgkm-only barrier: LDS drained, VMEM prefetch stays in flight.
__device__ __forceinline__ void lgkm_barrier() {
  __builtin_amdgcn_sched_barrier(0);
  asm volatile("s_waitcnt lgkmcnt(0)" ::: "memory");
  __builtin_amdgcn_s_barrier();
  __builtin_amdgcn_sched_barrier(0);
}

// Swapped-QK^T chunked-causal GQA attention, 16-wave blocks for 4 waves/SIMD.
// 256 blocks (b,n,hq,p) x 1024 threads. Wave owns a 16-row q-strip.
// S^T = K*Q^T (mfma16): lane owns q = lane&15 -> softmax needs only 2 shfls.
// O^T = V^T*P^T: q stays lane-local; rescale factor is a scalar per lane.
__global__ __launch_bounds__(1024, 4)
void attn_chunk(const float* __restrict__ Qg, const float* __restrict__ Kg,
                const float* __restrict__ Vg, float* __restrict__ Og) {
  __shared__ __attribute__((aligned(16))) bf16 ldsK[2][64 * 128];  // [key][d] ^((key&7)<<3)
  __shared__ __attribute__((aligned(16))) bf16 ldsV[2][128 * 64];  // [d][key] ^((d&7)<<3)
  __shared__ __attribute__((aligned(16))) bf16 ldsP[16][16][72];   // per-wave P relayout

  const int t = threadIdx.x, lane = t & 63, w = t >> 6;
  const int l15 = lane & 15, l4 = lane >> 4;

  // XCD grouping: 32 consecutive gids (half a (b,n)) per XCD -> K/V L2-local.
  const int bid = blockIdx.x;
  const int gid = (bid & 7) * 32 + (bid >> 3);
  const int p = gid & 1, hq = (gid >> 1) & 15, n = (gid >> 5) & 3, b = (gid >> 7) & 1;
  const int h = hq >> 1;

  // Wave -> 16-row strip; both p-blocks get needs {1,1,2,2,...,8,8}.
  const int st   = 4 * (w >> 1) + 2 * p + (w & 1);
  const int need = (w >> 1) + 1;            // 64-key tiles this wave computes
  const int qoff = 16 * (st & 3) + l15;     // q offset within diagonal tile

  // ---- Q fragments: B-operand, col=q=l15, k = dk*32 + 8*l4 + j ----
  bf16x8 qf[4];
  {
    const int    qg = n * kChunk + 16 * st + l15;
    const float* qp = Qg + ((size_t)(b * kS + qg) * kHq + hq) * kD;
#pragma unroll
    for (int dk = 0; dk < 4; ++dk) {
      f32x4 x0 = *(const f32x4*)(qp + dk * 32 + 8 * l4);
      f32x4 x1 = *(const f32x4*)(qp + dk * 32 + 8 * l4 + 4);
      bf16x8 v;
#pragma unroll
      for (int j = 0; j < 4; ++j) { v[j] = (bf16)(x0[j] * kScale); v[4 + j] = (bf16)(x1[j] * kScale); }
      qf[dk] = v;
    }
  }

  f32x4 o[8];  // O^T accum: d = 16*dt + 4*l4 + r, col q = l15
  const f32x4 z4 = {0.f, 0.f, 0.f, 0.f};
#pragma unroll
  for (int dt = 0; dt < 8; ++dt) o[dt] = z4;
  float m = -1e30f, l = 0.f;

  const float* kpz = Kg + ((size_t)(b * kS + n * kChunk) * kHkv + h) * kD;
  const float* vpz = Vg + ((size_t)(b * kS + n * kChunk) * kHkv + h) * kD;

  // staging coords (1024 threads / 64-key tile):
  const int sKey = t >> 5, sD4 = t & 31;  // K: key = 32*it + sKey, it 0..1
  const int vKp = t & 31, vD4 = t >> 5;   // V: keys {2vKp, 2vKp+1}, d4 = vD4

  f32x4 kf[2], va, vb;  // 1-deep T14 prefetch (16 VGPR)
  auto issue = [&](int kt) {
    const float* kp = kpz + (size_t)kt * 64 * kStrK;
    const float* vp = vpz + (size_t)kt * 64 * kStrK;
#pragma unroll
    for (int it = 0; it < 2; ++it)
      kf[it] = *(const f32x4*)(kp + (size_t)(32 * it + sKey) * kStrK + sD4 * 4);
    va = *(const f32x4*)(vp + (size_t)(2 * vKp) * kStrK + vD4 * 4);
    vb = *(const f32x4*)(vp + (size_t)(2 * vKp + 1) * kStrK + vD4 * 4);
  };
  auto stage = [&](int buf) {
#pragma unroll
    for (int it = 0; it < 2; ++it) {
      const int key = 32 * it + sKey;
      bf16x4 kb;
#pragma unroll
      for (int j = 0; j < 4; ++j) kb[j] = (bf16)kf[it][j];
      *(bf16x4*)&ldsK[buf][key * 128 + ((sD4 * 4) ^ ((key & 7) << 3))] = kb;
    }
#pragma unroll
    for (int j = 0; j < 4; ++j) {
      const int d = vD4 * 4 + j;
      U32B uu; uu.h = bf16x2{(bf16)va[j], (bf16)vb[j]};
      *(unsigned*)&ldsV[buf][d * 64 + ((2 * vKp) ^ ((d & 7) << 3))] = uu.u;
    }
  };

  auto compute = [&](int buf, bool diag) {
    // ---- QK^T: S^T[key][q], 16 MFMA ----
    f32x4 s4[4];
#pragma unroll
    for (int kb = 0; kb < 4; ++kb) s4[kb] = z4;
    __builtin_amdgcn_s_setprio(1);
#pragma unroll
    for (int kb = 0; kb < 4; ++kb) {
      const int key = kb * 16 + l15, swz = (key & 7) << 3;
      const bf16* kbp = &ldsK[buf][key * 128];
#pragma unroll
      for (int dk = 0; dk < 4; ++dk) {
        bf16x8 kfr = *(const bf16x8*)&kbp[(dk * 32 + 8 * l4) ^ swz];
        s4[kb] = MFMA16(kfr, qf[dk], s4[kb]);
      }
    }
    __builtin_amdgcn_s_setprio(0);
    if (diag) {
#pragma unroll
      for (int kb = 0; kb < 4; ++kb)
#pragma unroll
        for (int r = 0; r < 4; ++r)
          if (16 * kb + 4 * l4 + r > qoff) s4[kb][r] = -1e30f;
    }
    // ---- softmax: q=l15 lane-local; reduce across l4 group (2 shfls) ----
    float mx = fmaxf(fmaxf(fmaxf(s4[0][0], s4[0][1]), fmaxf(s4[0][2], s4[0][3])),
                     fmaxf(fmaxf(s4[1][0], s4[1][1]), fmaxf(s4[1][2], s4[1][3])));
    mx = fmaxf(mx, fmaxf(fmaxf(fmaxf(s4[2][0], s4[2][1]), fmaxf(s4[2][2], s4[2][3])),
                         fmaxf(fmaxf(s4[3][0], s4[3][1]), fmaxf(s4[3][2], s4[3][3]))));
    mx = fmaxf(mx, __shfl_xor(mx, 16, 64));
    mx = fmaxf(mx, __shfl_xor(mx, 32, 64));
    if (__any(mx > m + kThr)) {  // T13 defer-max
      const float mn = fmaxf(m, mx), c = exp2f(m - mn);
      l *= c;
#pragma unroll
      for (int dt = 0; dt < 8; ++dt)
#pragma unroll
        for (int r = 0; r < 4; ++r) o[dt][r] *= c;
      m = mn;
    }
    // ---- exp2, partial l, P -> per-wave LDS (contiguous bf16x4 per kb) ----
#pragma unroll
    for (int kb = 0; kb < 4; ++kb) {
      bf16x4 pb;
#pragma unroll
      for (int r = 0; r < 4; ++r) {
        const float pv = exp2f(s4[kb][r] - m);
        l += pv;
        pb[r] = (bf16)pv;
      }
      *(bf16x4*)&ldsP[w][l15][16 * kb + 4 * l4] = pb;
    }
    // ---- PV: O^T += V^T * P^T, 16 MFMA ----
    bf16x8 pa[2];
#pragma unroll
    for (int ks2 = 0; ks2 < 2; ++ks2)
      pa[ks2] = *(const bf16x8*)&ldsP[w][l15][ks2 * 32 + 8 * l4];
    __builtin_amdgcn_s_setprio(1);
#pragma unroll
    for (int dt = 0; dt < 8; ++dt) {
      const int d = dt * 16 + l15, swz = (d & 7) << 3;
      const bf16* vbp = &ldsV[buf][d * 64];
#pragma unroll
      for (int ks2 = 0; ks2 < 2; ++ks2) {
        bf16x8 vfr = *(const bf16x8*)&vbp[(ks2 * 32 + 8 * l4) ^ swz];
        o[dt] = MFMA16(vfr, pa[ks2], o[dt]);
      }
    }
    __builtin_amdgcn_s_setprio(0);
  };

  // ---- main loop: 1 lgkm-barrier/phase; loads for kt+1 in flight under compute(kt)
  issue(0);
  stage(0);
  lgkm_barrier();
#pragma unroll 1
  for (int kt = 0; kt < 8; ++kt) {
    const bool more = (kt + 1 < 8);
    if (more) issue(kt + 1);
    if (kt < need) compute(kt & 1, kt + 1 == need);
    if (more) {
      stage((kt + 1) & 1);
      lgkm_barrier();
    }
  }

  // ---- epilogue: reduce partial l across l4 group, divide, store O^T ----
  l += __shfl_xor(l, 16, 64);
  l += __shfl_xor(l, 32, 64);
  const float inv = 1.f / l;
  const int   qg  = n * kChunk + 16 * st + l15;
  float* op = Og + ((size_t)(b * kS + qg) * kHq + hq) * kD;
#pragma unroll
  for (int dt = 0; dt < 8; ++dt) {
    f32x4 stv;
#pragma unroll
    for (int r = 0; r < 4; ++r) stv[r] = o[dt][r] * inv;
    *(f32x4*)(op + dt * 16 + 4 * l4) = stv;
  }
}

extern "C" void kernel_launch(void* const* d_in, const int* in_sizes, int n_in,
                              void* d_out, int out_size, void* d_ws, size_t ws_size,
                              hipStream_t stream) {
  (void)in_sizes; (void)n_in; (void)d_ws; (void)ws_size; (void)out_size;
  const float* Q = (const float*)d_in[0];
  const float* K = (const float*)d_in[1];
  const float* V = (const float*)d_in[2];
  float* O = (float*)d_out;
  dim3 grid(256);    // (b2, n4, hq16, p2), XCD-grouped; 1 block/CU
  dim3 block(1024);  // 16 waves x 16-row q-strips -> 4 waves/SIMD
  hipLaunchKernelGGL(attn_chunk, grid, block, 0, stream, Q, K, V, O);
}